// Round 4
// baseline (84580.908 us; speedup 1.0000x reference)
//
#include <hip/hip_runtime.h>
#include <cstdint>

// Problem dims
// B=64 T=512 S=500 M=80 E=512 P=256 H=1024 A=128 F_LOC=32 K_LOC=31

__device__ __forceinline__ void tf2x32(uint32_t k0, uint32_t k1, uint32_t& x0, uint32_t& x1) {
  uint32_t ks2 = k0 ^ k1 ^ 0x1BD11BDAu;
  x0 += k0; x1 += k1;
#define TFR(r) { x0 += x1; x1 = (x1 << (r)) | (x1 >> (32 - (r))); x1 ^= x0; }
  TFR(13) TFR(15) TFR(26) TFR(6)
  x0 += k1; x1 += ks2 + 1u;
  TFR(17) TFR(29) TFR(16) TFR(24)
  x0 += ks2; x1 += k0 + 2u;
  TFR(13) TFR(15) TFR(26) TFR(6)
  x0 += k0; x1 += k1 + 3u;
  TFR(17) TFR(29) TFR(16) TFR(24)
  x0 += k1; x1 += ks2 + 4u;
  TFR(13) TFR(15) TFR(26) TFR(6)
  x0 += ks2; x1 += k0 + 5u;
#undef TFR
}

__device__ __forceinline__ uint32_t rng_bits(uint32_t k0, uint32_t k1, uint32_t idx) {
  uint32_t x0 = 0u, x1 = idx;
  tf2x32(k0, k1, x0, x1);
  return x0 ^ x1;
}

__device__ __forceinline__ float rng_u01(uint32_t k0, uint32_t k1, uint32_t idx) {
  uint32_t b = rng_bits(k0, k1, idx);
  return __uint_as_float((b >> 9) | 0x3f800000u) - 1.0f;
}

__device__ __forceinline__ float sigmf(float x) { return 1.0f / (1.0f + expf(-x)); }

// ---------------- folded dropout keys: kf[t] = threefry(key(7), [0, t]) -------------
__global__ void k_fold(uint32_t* __restrict__ kf) {
  int t = blockIdx.x * 256 + threadIdx.x;
  if (t < 1000) {
    uint32_t x0 = 0u, x1 = (uint32_t)t;
    tf2x32(0u, 7u, x0, x1);
    kf[2 * t] = x0; kf[2 * t + 1] = x1;
  }
}

// ---------------- processed_memory[b,t,a] = sum_e memory[b,t,e]*wm[a,e] ------------
__global__ __launch_bounds__(256) void k_pm(const float* __restrict__ mem,
                                            const float* __restrict__ wm,
                                            float* __restrict__ pm) {
  const int row0 = blockIdx.x * 8;  // flat (b*512+t)
  __shared__ float sm[8][512];
  const float4* src = (const float4*)(mem + (size_t)row0 * 512);
  float4* dst = (float4*)&sm[0][0];
  for (int i = threadIdx.x; i < 8 * 128; i += 256) dst[i] = src[i];
  __syncthreads();
  const int a = threadIdx.x & 127;
  const int rh = threadIdx.x >> 7;
  float acc[4] = {0.f, 0.f, 0.f, 0.f};
  for (int e = 0; e < 512; e += 4) {
    float4 w4 = *(const float4*)&wm[a * 512 + e];
#pragma unroll
    for (int r = 0; r < 4; r++) {
      acc[r] += sm[rh * 4 + r][e] * w4.x + sm[rh * 4 + r][e + 1] * w4.y +
                sm[rh * 4 + r][e + 2] * w4.z + sm[rh * 4 + r][e + 3] * w4.w;
    }
  }
#pragma unroll
  for (int r = 0; r < 4; r++) pm[(size_t)(row0 + rh * 4 + r) * 128 + a] = acc[r];
}

// ---------------- prenet layer1 --------------------------------------------------
__global__ __launch_bounds__(256) void k_prenet1(const float* __restrict__ din,
                                                 const float* __restrict__ w1,
                                                 float* __restrict__ buf) {
  const int r0 = blockIdx.x * 8;
  const int tid = threadIdx.x;
  __shared__ float xin[8][80];
  for (int i = tid; i < 640; i += 256) {
    int rr = i / 80, k = i - rr * 80;
    int r = r0 + rr;
    int s = r >> 6, b = r & 63;
    xin[rr][k] = (s == 0) ? 0.0f : din[((size_t)b * 500 + (s - 1)) * 80 + k];
  }
  __syncthreads();
  const int j = tid;
  float acc[8] = {};
  for (int k = 0; k < 80; k++) {
    float wv = w1[j * 80 + k];
#pragma unroll
    for (int i = 0; i < 8; i++) acc[i] += xin[i][k] * wv;
  }
#pragma unroll
  for (int i = 0; i < 8; i++) {
    int r = r0 + i;
    float x = fmaxf(acc[i], 0.0f);
    float u = rng_u01(0u, 101u, (uint32_t)(r * 256 + j));
    x = (u < 0.5f) ? x * 2.0f : 0.0f;
    buf[(size_t)r * 256 + j] = x;
  }
}

// ---------------- prenet layer2 (in-place) ----------------------------------------
__global__ __launch_bounds__(256) void k_prenet2(float* __restrict__ buf,
                                                 const float* __restrict__ w2) {
  const int r0 = blockIdx.x * 8;
  const int tid = threadIdx.x;
  __shared__ float xin[8][256];
  for (int i = tid; i < 2048; i += 256) xin[i >> 8][i & 255] = buf[(size_t)r0 * 256 + i];
  __syncthreads();
  const int j = tid;
  float acc[8] = {};
  for (int k = 0; k < 256; k++) {
    float wv = w2[j * 256 + k];
#pragma unroll
    for (int i = 0; i < 8; i++) acc[i] += xin[i][k] * wv;
  }
#pragma unroll
  for (int i = 0; i < 8; i++) {
    int r = r0 + i;
    float x = fmaxf(acc[i], 0.0f);
    float u = rng_u01(0u, 102u, (uint32_t)(r * 256 + j));
    x = (u < 0.5f) ? x * 2.0f : 0.0f;
    buf[(size_t)r * 256 + j] = x;
  }
}

// ---------------- LSTM gate GEMM, K-split partials (vectorized staging) -----------
__global__ __launch_bounds__(256) void k_gemm_part(
    const float* __restrict__ s0, int L0,
    const float* __restrict__ s1, int L1,
    const float* __restrict__ sh,
    const float* __restrict__ wih, const float* __restrict__ whh,
    int LIH, int chunk, float* __restrict__ part) {
  const int jbase = blockIdx.x * 64;
  const int k0 = blockIdx.y * chunk;
  const int NC = chunk >> 5;
  __shared__ float xs[32][68];
  __shared__ float ws[32][68];
  const int tid = threadIdx.x;
  const int row = tid & 63;
  const int q8 = (tid >> 6) << 3;
  const int bq = tid & 15, jq = tid >> 4;
  const int jrow = jbase + row;

  float4 rx0, rx1, rw0, rw1;
  auto loadt = [&](int kb, float4& x0r, float4& x1r, float4& w0r, float4& w1r) {
    const float* xp; int xst, xof;
    if (kb < L0)            { xp = s0; xst = L0;   xof = kb; }
    else if (kb < L0 + L1)  { xp = s1; xst = L1;   xof = kb - L0; }
    else                    { xp = sh; xst = 1024; xof = kb - L0 - L1; }
    const float* xr = xp + (size_t)row * xst + xof + q8;
    x0r = *(const float4*)xr; x1r = *(const float4*)(xr + 4);
    const float* wp; int wst, wof;
    if (kb < LIH) { wp = wih; wst = LIH;  wof = kb; }
    else          { wp = whh; wst = 1024; wof = kb - LIH; }
    const float* wr = wp + (size_t)jrow * wst + wof + q8;
    w0r = *(const float4*)wr; w1r = *(const float4*)(wr + 4);
  };

  loadt(k0, rx0, rx1, rw0, rw1);
  float acc[4][4] = {};
  for (int c = 0; c < NC; ++c) {
    __syncthreads();
#pragma unroll
    for (int i = 0; i < 4; i++) {
      xs[q8 + i][row]     = ((const float*)&rx0)[i];
      xs[q8 + 4 + i][row] = ((const float*)&rx1)[i];
      ws[q8 + i][row]     = ((const float*)&rw0)[i];
      ws[q8 + 4 + i][row] = ((const float*)&rw1)[i];
    }
    __syncthreads();
    if (c + 1 < NC) loadt(k0 + (c + 1) * 32, rx0, rx1, rw0, rw1);
#pragma unroll
    for (int kk = 0; kk < 32; kk++) {
      float4 xv = *(const float4*)&xs[kk][bq * 4];
      float4 wv = *(const float4*)&ws[kk][jq * 4];
      acc[0][0] = fmaf(wv.x, xv.x, acc[0][0]); acc[0][1] = fmaf(wv.x, xv.y, acc[0][1]);
      acc[0][2] = fmaf(wv.x, xv.z, acc[0][2]); acc[0][3] = fmaf(wv.x, xv.w, acc[0][3]);
      acc[1][0] = fmaf(wv.y, xv.x, acc[1][0]); acc[1][1] = fmaf(wv.y, xv.y, acc[1][1]);
      acc[1][2] = fmaf(wv.y, xv.z, acc[1][2]); acc[1][3] = fmaf(wv.y, xv.w, acc[1][3]);
      acc[2][0] = fmaf(wv.z, xv.x, acc[2][0]); acc[2][1] = fmaf(wv.z, xv.y, acc[2][1]);
      acc[2][2] = fmaf(wv.z, xv.z, acc[2][2]); acc[2][3] = fmaf(wv.z, xv.w, acc[2][3]);
      acc[3][0] = fmaf(wv.w, xv.x, acc[3][0]); acc[3][1] = fmaf(wv.w, xv.y, acc[3][1]);
      acc[3][2] = fmaf(wv.w, xv.z, acc[3][2]); acc[3][3] = fmaf(wv.w, xv.w, acc[3][3]);
    }
  }
  float* pbase = part + (size_t)blockIdx.y * 64 * 4096;
#pragma unroll
  for (int bb = 0; bb < 4; bb++) {
    int b = bq * 4 + bb;
    float4 o = make_float4(acc[0][bb], acc[1][bb], acc[2][bb], acc[3][bb]);
    *(float4*)&pbase[(size_t)b * 4096 + jbase + jq * 4] = o;
  }
}

// =================== fused per-b kernel ============================================
// Phase 1 (s>0): dec LSTM pointwise(s-1) + dropout + mel/gate(s-1)
// Phase 2: attn LSTM pointwise(s) + dropout + q = ah @ Wq^T
// Phase 3: energies (4 t-tiles of 128): conv + loc-dense + tanh·v
// Phase 4: softmax + aw/awc/align
// Phase 5: ctx = aw @ memory

struct FP {
  const float* part_a; const float* part_d;
  const float* abih; const float* abhh;
  const float* dbih; const float* dbhh;
  float* ac; float* ah; float* dc; float* dh;
  const uint32_t* kf; int s;
  const float* wq; const float* wconv; const float* wld; const float* av;
  const float* pm; const int* mlen;
  float* aw; float* awc;
  const float* memory;
  const float* ctx_prev; float* ctx_cur;
  const float* projw; const float* projb;
  const float* gatew; const float* gateb;
  float* out_mel; float* out_gate; float* out_align;
};

union FU {
  struct { float hcs[1536]; float ored[128][9]; } mg;                       // 10.5 KB
  struct { float ahs[1024]; float qred[128][9]; } ap;                       //  8.5 KB
  struct { float sa[2][160]; float sloc[128][33]; float spart[128][8]; } en; // 21.8 KB
  struct { float cred[8][128][4]; } cx;                                     // 16.0 KB
};

__device__ __forceinline__ void dec_pointwise_melgate(
    const FP& p, FU& u, int b, int tid, int sm1) {
  const uint32_t fk0 = p.kf[2 * (2 * sm1 + 1)], fk1 = p.kf[2 * (2 * sm1 + 1) + 1];
  {
    const int h = tid;
    float gi = p.dbih[h] + p.dbhh[h];
    float gf = p.dbih[h + 1024] + p.dbhh[h + 1024];
    float gg = p.dbih[h + 2048] + p.dbhh[h + 2048];
    float go = p.dbih[h + 3072] + p.dbhh[h + 3072];
    for (int ks = 0; ks < 8; ks++) {
      const float* pp = p.part_d + (size_t)(ks * 64 + b) * 4096;
      gi += pp[h]; gf += pp[h + 1024]; gg += pp[h + 2048]; go += pp[h + 3072];
    }
    float c = sigmf(gf) * p.dc[b * 1024 + h] + sigmf(gi) * tanhf(gg);
    float hn = sigmf(go) * tanhf(c);
    p.dc[b * 1024 + h] = c;
    float uu = rng_u01(fk0, fk1, (uint32_t)(b * 1024 + h));
    hn = (uu < 0.9f) ? hn / 0.9f : 0.0f;
    p.dh[b * 1024 + h] = hn;
    u.mg.hcs[h] = hn;
  }
  if (tid < 512) u.mg.hcs[1024 + tid] = p.ctx_prev[b * 512 + tid];
  __syncthreads();
  {
    const int mm = tid & 127, seg = tid >> 7;   // 8 segments of 192
    if (mm <= 80) {
      const float* wr = ((mm < 80) ? (p.projw + (size_t)mm * 1536) : p.gatew) + seg * 192;
      const float* hs = u.mg.hcs + seg * 192;
      float a0 = 0, a1 = 0, a2 = 0, a3 = 0;
#pragma unroll 4
      for (int k = 0; k < 192; k += 4) {
        float4 w4 = *(const float4*)(wr + k);
        float4 h4 = *(const float4*)(hs + k);
        a0 = fmaf(h4.x, w4.x, a0); a1 = fmaf(h4.y, w4.y, a1);
        a2 = fmaf(h4.z, w4.z, a2); a3 = fmaf(h4.w, w4.w, a3);
      }
      u.mg.ored[mm][seg] = (a0 + a1) + (a2 + a3);
    }
  }
  __syncthreads();
  if (tid <= 80) {
    float tot = 0.f;
#pragma unroll
    for (int i = 0; i < 8; i++) tot += u.mg.ored[tid][i];
    if (tid < 80) p.out_mel[(size_t)b * 40000 + (size_t)sm1 * 80 + tid] = tot + p.projb[tid];
    else          p.out_gate[b * 500 + sm1] = tot + p.gateb[0];
  }
  __syncthreads();  // before LDS union reuse
}

__global__ __launch_bounds__(1024) void k_fused(FP p) {
  const int b = blockIdx.x, tid = threadIdx.x;
  __shared__ FU u;
  __shared__ float q_s[128], sv[128], se[512], red[8];
  __shared__ float sw[1984];
  __shared__ float sld[128][32];

  // ---- Phase 1: finish decoder side of step s-1 ----
  if (p.s > 0) dec_pointwise_melgate(p, u, b, tid, p.s - 1);

  // ---- Phase 2: attn LSTM pointwise + q ----
  {
    const uint32_t fk0 = p.kf[4 * p.s], fk1 = p.kf[4 * p.s + 1];
    const int h = tid;
    float gi = p.abih[h] + p.abhh[h];
    float gf = p.abih[h + 1024] + p.abhh[h + 1024];
    float gg = p.abih[h + 2048] + p.abhh[h + 2048];
    float go = p.abih[h + 3072] + p.abhh[h + 3072];
    for (int ks = 0; ks < 8; ks++) {
      const float* pp = p.part_a + (size_t)(ks * 64 + b) * 4096;
      gi += pp[h]; gf += pp[h + 1024]; gg += pp[h + 2048]; go += pp[h + 3072];
    }
    float c = sigmf(gf) * p.ac[b * 1024 + h] + sigmf(gi) * tanhf(gg);
    float hn = sigmf(go) * tanhf(c);
    p.ac[b * 1024 + h] = c;
    float uu = rng_u01(fk0, fk1, (uint32_t)(b * 1024 + h));
    hn = (uu < 0.9f) ? hn / 0.9f : 0.0f;
    p.ah[b * 1024 + h] = hn;
    u.ap.ahs[h] = hn;
  }
  __syncthreads();
  {
    const int a = tid & 127, seg = tid >> 7;   // 8 segments of 128
    const float* wr = p.wq + (size_t)a * 1024 + seg * 128;
    const float* hs = u.ap.ahs + seg * 128;
    float a0 = 0, a1 = 0, a2 = 0, a3 = 0;
#pragma unroll 8
    for (int k = 0; k < 128; k += 4) {
      float4 w4 = *(const float4*)(wr + k);
      float4 h4 = *(const float4*)(hs + k);
      a0 = fmaf(h4.x, w4.x, a0); a1 = fmaf(h4.y, w4.y, a1);
      a2 = fmaf(h4.z, w4.z, a2); a3 = fmaf(h4.w, w4.w, a3);
    }
    u.ap.qred[a][seg] = (a0 + a1) + (a2 + a3);
  }
  __syncthreads();
  if (tid < 128) {
    float t = 0.f;
#pragma unroll
    for (int i = 0; i < 8; i++) t += u.ap.qred[tid][i];
    q_s[tid] = t;
  }
  // stage persistent weights (no barrier needed before first tile-loop barrier)
  for (int i = tid; i < 1984; i += 1024) sw[i] = p.wconv[i];
  for (int i = tid; i < 4096; i += 1024) ((float*)sld)[i] = p.wld[i];
  if (tid >= 128 && tid < 256) sv[tid - 128] = p.av[tid - 128];

  // ---- Phase 3: energies in 4 t-tiles of 128 ----
  const int len = p.mlen[b];
  for (int tile = 0; tile < 4; tile++) {
    const int t0 = tile * 128;
    __syncthreads();   // qred reads done / prev-tile sa reads done
    for (int i = tid; i < 158; i += 1024) {
      int tt = t0 - 15 + i;
      bool ok = (tt >= 0 && tt < 512);
      u.en.sa[0][i] = ok ? p.aw[b * 512 + tt] : 0.f;
      u.en.sa[1][i] = ok ? p.awc[b * 512 + tt] : 0.f;
    }
    __syncthreads();
    {
      const int t = tid & 127, fq = tid >> 7;
#pragma unroll
      for (int df = 0; df < 4; df++) {
        int f = fq * 4 + df;
        const float* w0 = sw + f * 62;
        const float* w1 = w0 + 31;
        float a = 0.f;
#pragma unroll
        for (int k = 0; k < 31; k++)
          a = fmaf(u.en.sa[0][t + k], w0[k], fmaf(u.en.sa[1][t + k], w1[k], a));
        u.en.sloc[t][f] = a;
      }
    }
    __syncthreads();
    {
      const int t = tid & 127, aq = tid >> 7;
      const int tt = t0 + t;
      float acc = 0.f;
      if (tt < len) {
        const float* pmr = p.pm + (size_t)(b * 512 + tt) * 128;
        const float* slr = u.en.sloc[t];
        for (int j = 0; j < 16; j++) {
          int a = aq * 16 + j;
          const float* wl = sld[a];
          float pl = 0.f;
#pragma unroll
          for (int f4 = 0; f4 < 8; f4++) {
            float4 w4 = *(const float4*)(wl + f4 * 4);
            pl = fmaf(slr[f4 * 4], w4.x, pl); pl = fmaf(slr[f4 * 4 + 1], w4.y, pl);
            pl = fmaf(slr[f4 * 4 + 2], w4.z, pl); pl = fmaf(slr[f4 * 4 + 3], w4.w, pl);
          }
          float x = q_s[a] + pl + pmr[a];
          float ex = __expf(2.0f * x);
          acc = fmaf(sv[a], 1.0f - 2.0f / (ex + 1.0f), acc);
        }
      }
      u.en.spart[t][aq] = acc;
    }
    __syncthreads();
    if (tid < 128) {
      int tt = t0 + tid;
      float e = 0.f;
#pragma unroll
      for (int i = 0; i < 8; i++) e += u.en.spart[tid][i];
      se[tt] = (tt < len) ? e : -1e9f;
    }
  }
  __syncthreads();

  // ---- Phase 4: softmax + aw/awc/align ----
  float x = 0.f;
  if (tid < 512) {
    float e = se[tid];
    float m = e;
#pragma unroll
    for (int off = 32; off; off >>= 1) m = fmaxf(m, __shfl_xor(m, off, 64));
    if ((tid & 63) == 0) red[tid >> 6] = m;
  }
  __syncthreads();
  const float maxv = fmaxf(fmaxf(fmaxf(red[0], red[1]), fmaxf(red[2], red[3])),
                           fmaxf(fmaxf(red[4], red[5]), fmaxf(red[6], red[7])));
  if (tid < 512) {
    x = (tid < len) ? __expf(se[tid] - maxv) : 0.0f;
    float sm = x;
#pragma unroll
    for (int off = 32; off; off >>= 1) sm += __shfl_xor(sm, off, 64);
    __syncthreads();
    if ((tid & 63) == 0) red[tid >> 6] = sm;
  } else {
    __syncthreads();
  }
  __syncthreads();
  const float tot = ((red[0] + red[1]) + (red[2] + red[3])) +
                    ((red[4] + red[5]) + (red[6] + red[7]));
  if (tid < 512) {
    float awv = x / tot;
    se[tid] = awv;
    p.aw[b * 512 + tid] = awv;
    p.awc[b * 512 + tid] += awv;
    p.out_align[(size_t)b * 256000 + (size_t)p.s * 512 + tid] = awv;
  }
  __syncthreads();

  // ---- Phase 5: ctx = aw @ memory ----
  {
    const int e4 = tid & 127, tq = tid >> 7;
    const float4* mb = (const float4*)(p.memory + (size_t)b * 262144) + e4;
    float4 c = make_float4(0.f, 0.f, 0.f, 0.f);
    for (int t2 = tq; t2 < len; t2 += 8) {
      float w = se[t2];
      float4 mv = mb[(size_t)t2 * 128];
      c.x = fmaf(w, mv.x, c.x); c.y = fmaf(w, mv.y, c.y);
      c.z = fmaf(w, mv.z, c.z); c.w = fmaf(w, mv.w, c.w);
    }
    *(float4*)&u.cx.cred[tq][e4][0] = c;
  }
  __syncthreads();
  if (tid < 128) {
    float4 c = *(float4*)&u.cx.cred[0][tid][0];
#pragma unroll
    for (int i = 1; i < 8; i++) {
      float4 d = *(float4*)&u.cx.cred[i][tid][0];
      c.x += d.x; c.y += d.y; c.z += d.z; c.w += d.w;
    }
    *(float4*)&p.ctx_cur[b * 512 + tid * 4] = c;
  }
}

// ---------------- epilogue: dec pointwise + mel/gate for s=499 --------------------
__global__ __launch_bounds__(1024) void k_dec_final(FP p) {
  const int b = blockIdx.x, tid = threadIdx.x;
  __shared__ FU u;
  dec_pointwise_melgate(p, u, b, tid, 499);
}

extern "C" void kernel_launch(void* const* d_in, const int* in_sizes, int n_in,
                              void* d_out, int out_size, void* d_ws, size_t ws_size,
                              hipStream_t stream) {
  const float* memory = (const float*)d_in[0];
  const int*   mlen   = (const int*)d_in[1];
  const float* dec_in = (const float*)d_in[2];
  const float* pw1    = (const float*)d_in[3];
  const float* pw2    = (const float*)d_in[4];
  const float* awih   = (const float*)d_in[5];
  const float* awhh   = (const float*)d_in[6];
  const float* abih   = (const float*)d_in[7];
  const float* abhh   = (const float*)d_in[8];
  const float* dwih   = (const float*)d_in[9];
  const float* dwhh   = (const float*)d_in[10];
  const float* dbih   = (const float*)d_in[11];
  const float* dbhh   = (const float*)d_in[12];
  const float* wq     = (const float*)d_in[13];
  const float* wm     = (const float*)d_in[14];
  const float* av     = (const float*)d_in[15];
  const float* wconv  = (const float*)d_in[16];
  const float* wld    = (const float*)d_in[17];
  const float* projw  = (const float*)d_in[18];
  const float* projb  = (const float*)d_in[19];
  const float* gatew  = (const float*)d_in[20];
  const float* gateb  = (const float*)d_in[21];

  float* out       = (float*)d_out;
  float* out_mel   = out;                 // B*S*M = 2,560,000
  float* out_gate  = out + 2560000;       // B*S   = 32,000
  float* out_align = out + 2592000;       // B*S*T = 16,384,000

  float* ws      = (float*)d_ws;
  float* pm      = ws;                     // 4,194,304
  float* prenet  = pm + 4194304;           // 8,192,000
  float* part_a  = prenet + 8192000;       // 2,097,152
  float* part_d  = part_a + 2097152;       // 2,097,152
  float* st      = part_d + 2097152;       // states (memset 0):
  float* ah   = st;                        // 65536
  float* ac   = ah + 65536;
  float* dh   = ac + 65536;
  float* dc   = dh + 65536;
  float* aw   = dc + 65536;                // 32768
  float* awc  = aw + 32768;
  float* ctx0 = awc + 32768;               // 32768
  float* ctx1 = ctx0 + 32768;              // 32768
  uint32_t* kf = (uint32_t*)(ctx1 + 32768);  // 2000 u32

  hipMemsetAsync(st, 0, (size_t)(4 * 65536 + 4 * 32768) * sizeof(float), stream);
  k_fold<<<4, 256, 0, stream>>>(kf);
  k_pm<<<4096, 256, 0, stream>>>(memory, wm, pm);
  k_prenet1<<<4000, 256, 0, stream>>>(dec_in, pw1, prenet);
  k_prenet2<<<4000, 256, 0, stream>>>(prenet, pw2);

  FP fp;
  fp.part_a = part_a; fp.part_d = part_d;
  fp.abih = abih; fp.abhh = abhh; fp.dbih = dbih; fp.dbhh = dbhh;
  fp.ac = ac; fp.ah = ah; fp.dc = dc; fp.dh = dh;
  fp.kf = kf;
  fp.wq = wq; fp.wconv = wconv; fp.wld = wld; fp.av = av;
  fp.pm = pm; fp.mlen = mlen;
  fp.aw = aw; fp.awc = awc;
  fp.memory = memory;
  fp.projw = projw; fp.projb = projb; fp.gatew = gatew; fp.gateb = gateb;
  fp.out_mel = out_mel; fp.out_gate = out_gate; fp.out_align = out_align;

  float* ctxb[2] = { ctx0, ctx1 };
  for (int s = 0; s < 500; s++) {
    float* ctx_prev = ctxb[(s + 1) & 1];  // ctx(s-1); zeros at s=0 (ctx1 memset)
    float* ctx_cur  = ctxb[s & 1];
    // attention LSTM: x = [prenet_xt(256) | ctx(s-1)(512) | ah(s-1)] ; K = 1792
    k_gemm_part<<<dim3(64, 8), 256, 0, stream>>>(prenet + (size_t)s * 16384, 256,
                                                 ctx_prev, 512, ah, awih, awhh, 768, 224, part_a);
    fp.s = s; fp.ctx_prev = ctx_prev; fp.ctx_cur = ctx_cur;
    k_fused<<<64, 1024, 0, stream>>>(fp);
    // decoder LSTM: x = [ah(s)(1024) | ctx(s)(512) | dh(s-1)] ; K = 2560
    k_gemm_part<<<dim3(64, 8), 256, 0, stream>>>(ah, 1024, ctx_cur, 512, dh,
                                                 dwih, dwhh, 1536, 320, part_d);
  }
  fp.ctx_prev = ctxb[1];  // ctx(499): 499&1 = 1
  k_dec_final<<<64, 1024, 0, stream>>>(fp);
}

// Round 5
// 62614.319 us; speedup vs baseline: 1.3508x; 1.3508x over previous
//
#include <hip/hip_runtime.h>
#include <cstdint>

// Problem dims
// B=64 T=512 S=500 M=80 E=512 P=256 H=1024 A=128 F_LOC=32 K_LOC=31

__device__ __forceinline__ void tf2x32(uint32_t k0, uint32_t k1, uint32_t& x0, uint32_t& x1) {
  uint32_t ks2 = k0 ^ k1 ^ 0x1BD11BDAu;
  x0 += k0; x1 += k1;
#define TFR(r) { x0 += x1; x1 = (x1 << (r)) | (x1 >> (32 - (r))); x1 ^= x0; }
  TFR(13) TFR(15) TFR(26) TFR(6)
  x0 += k1; x1 += ks2 + 1u;
  TFR(17) TFR(29) TFR(16) TFR(24)
  x0 += ks2; x1 += k0 + 2u;
  TFR(13) TFR(15) TFR(26) TFR(6)
  x0 += k0; x1 += k1 + 3u;
  TFR(17) TFR(29) TFR(16) TFR(24)
  x0 += k1; x1 += ks2 + 4u;
  TFR(13) TFR(15) TFR(26) TFR(6)
  x0 += ks2; x1 += k0 + 5u;
#undef TFR
}

__device__ __forceinline__ uint32_t rng_bits(uint32_t k0, uint32_t k1, uint32_t idx) {
  uint32_t x0 = 0u, x1 = idx;
  tf2x32(k0, k1, x0, x1);
  return x0 ^ x1;
}

__device__ __forceinline__ float rng_u01(uint32_t k0, uint32_t k1, uint32_t idx) {
  uint32_t b = rng_bits(k0, k1, idx);
  return __uint_as_float((b >> 9) | 0x3f800000u) - 1.0f;
}

__device__ __forceinline__ float sigmf(float x) { return 1.0f / (1.0f + expf(-x)); }

// ---------------- folded dropout keys: kf[t] = threefry(key(7), [0, t]) -------------
__global__ void k_fold(uint32_t* __restrict__ kf) {
  int t = blockIdx.x * 256 + threadIdx.x;
  if (t < 1000) {
    uint32_t x0 = 0u, x1 = (uint32_t)t;
    tf2x32(0u, 7u, x0, x1);
    kf[2 * t] = x0; kf[2 * t + 1] = x1;
  }
}

// ---------------- processed_memory[b,t,a] = sum_e memory[b,t,e]*wm[a,e] ------------
__global__ __launch_bounds__(256) void k_pm(const float* __restrict__ mem,
                                            const float* __restrict__ wm,
                                            float* __restrict__ pm) {
  const int row0 = blockIdx.x * 8;  // flat (b*512+t)
  __shared__ float sm[8][512];
  const float4* src = (const float4*)(mem + (size_t)row0 * 512);
  float4* dst = (float4*)&sm[0][0];
  for (int i = threadIdx.x; i < 8 * 128; i += 256) dst[i] = src[i];
  __syncthreads();
  const int a = threadIdx.x & 127;
  const int rh = threadIdx.x >> 7;
  float acc[4] = {0.f, 0.f, 0.f, 0.f};
  for (int e = 0; e < 512; e += 4) {
    float4 w4 = *(const float4*)&wm[a * 512 + e];
#pragma unroll
    for (int r = 0; r < 4; r++) {
      acc[r] += sm[rh * 4 + r][e] * w4.x + sm[rh * 4 + r][e + 1] * w4.y +
                sm[rh * 4 + r][e + 2] * w4.z + sm[rh * 4 + r][e + 3] * w4.w;
    }
  }
#pragma unroll
  for (int r = 0; r < 4; r++) pm[(size_t)(row0 + rh * 4 + r) * 128 + a] = acc[r];
}

// ---------------- prenet layer1 --------------------------------------------------
__global__ __launch_bounds__(256) void k_prenet1(const float* __restrict__ din,
                                                 const float* __restrict__ w1,
                                                 float* __restrict__ buf) {
  const int r0 = blockIdx.x * 8;
  const int tid = threadIdx.x;
  __shared__ float xin[8][80];
  for (int i = tid; i < 640; i += 256) {
    int rr = i / 80, k = i - rr * 80;
    int r = r0 + rr;
    int s = r >> 6, b = r & 63;
    xin[rr][k] = (s == 0) ? 0.0f : din[((size_t)b * 500 + (s - 1)) * 80 + k];
  }
  __syncthreads();
  const int j = tid;
  float acc[8] = {};
  for (int k = 0; k < 80; k++) {
    float wv = w1[j * 80 + k];
#pragma unroll
    for (int i = 0; i < 8; i++) acc[i] += xin[i][k] * wv;
  }
#pragma unroll
  for (int i = 0; i < 8; i++) {
    int r = r0 + i;
    float x = fmaxf(acc[i], 0.0f);
    float u = rng_u01(0u, 101u, (uint32_t)(r * 256 + j));
    x = (u < 0.5f) ? x * 2.0f : 0.0f;
    buf[(size_t)r * 256 + j] = x;
  }
}

// ---------------- prenet layer2 (in-place) ----------------------------------------
__global__ __launch_bounds__(256) void k_prenet2(float* __restrict__ buf,
                                                 const float* __restrict__ w2) {
  const int r0 = blockIdx.x * 8;
  const int tid = threadIdx.x;
  __shared__ float xin[8][256];
  for (int i = tid; i < 2048; i += 256) xin[i >> 8][i & 255] = buf[(size_t)r0 * 256 + i];
  __syncthreads();
  const int j = tid;
  float acc[8] = {};
  for (int k = 0; k < 256; k++) {
    float wv = w2[j * 256 + k];
#pragma unroll
    for (int i = 0; i < 8; i++) acc[i] += xin[i][k] * wv;
  }
#pragma unroll
  for (int i = 0; i < 8; i++) {
    int r = r0 + i;
    float x = fmaxf(acc[i], 0.0f);
    float u = rng_u01(0u, 102u, (uint32_t)(r * 256 + j));
    x = (u < 0.5f) ? x * 2.0f : 0.0f;
    buf[(size_t)r * 256 + j] = x;
  }
}

// ---------------- LSTM gate GEMM, K-split partials (vectorized staging) -----------
__global__ __launch_bounds__(256) void k_gemm_part(
    const float* __restrict__ s0, int L0,
    const float* __restrict__ s1, int L1,
    const float* __restrict__ sh,
    const float* __restrict__ wih, const float* __restrict__ whh,
    int LIH, int chunk, float* __restrict__ part) {
  const int jbase = blockIdx.x * 64;
  const int k0 = blockIdx.y * chunk;
  const int NC = chunk >> 5;
  __shared__ float xs[32][68];
  __shared__ float ws[32][68];
  const int tid = threadIdx.x;
  const int row = tid & 63;
  const int q8 = (tid >> 6) << 3;
  const int bq = tid & 15, jq = tid >> 4;
  const int jrow = jbase + row;

  float4 rx0, rx1, rw0, rw1;
  auto loadt = [&](int kb, float4& x0r, float4& x1r, float4& w0r, float4& w1r) {
    const float* xp; int xst, xof;
    if (kb < L0)            { xp = s0; xst = L0;   xof = kb; }
    else if (kb < L0 + L1)  { xp = s1; xst = L1;   xof = kb - L0; }
    else                    { xp = sh; xst = 1024; xof = kb - L0 - L1; }
    const float* xr = xp + (size_t)row * xst + xof + q8;
    x0r = *(const float4*)xr; x1r = *(const float4*)(xr + 4);
    const float* wp; int wst, wof;
    if (kb < LIH) { wp = wih; wst = LIH;  wof = kb; }
    else          { wp = whh; wst = 1024; wof = kb - LIH; }
    const float* wr = wp + (size_t)jrow * wst + wof + q8;
    w0r = *(const float4*)wr; w1r = *(const float4*)(wr + 4);
  };

  loadt(k0, rx0, rx1, rw0, rw1);
  float acc[4][4] = {};
  for (int c = 0; c < NC; ++c) {
    __syncthreads();
#pragma unroll
    for (int i = 0; i < 4; i++) {
      xs[q8 + i][row]     = ((const float*)&rx0)[i];
      xs[q8 + 4 + i][row] = ((const float*)&rx1)[i];
      ws[q8 + i][row]     = ((const float*)&rw0)[i];
      ws[q8 + 4 + i][row] = ((const float*)&rw1)[i];
    }
    __syncthreads();
    if (c + 1 < NC) loadt(k0 + (c + 1) * 32, rx0, rx1, rw0, rw1);
#pragma unroll
    for (int kk = 0; kk < 32; kk++) {
      float4 xv = *(const float4*)&xs[kk][bq * 4];
      float4 wv = *(const float4*)&ws[kk][jq * 4];
      acc[0][0] = fmaf(wv.x, xv.x, acc[0][0]); acc[0][1] = fmaf(wv.x, xv.y, acc[0][1]);
      acc[0][2] = fmaf(wv.x, xv.z, acc[0][2]); acc[0][3] = fmaf(wv.x, xv.w, acc[0][3]);
      acc[1][0] = fmaf(wv.y, xv.x, acc[1][0]); acc[1][1] = fmaf(wv.y, xv.y, acc[1][1]);
      acc[1][2] = fmaf(wv.y, xv.z, acc[1][2]); acc[1][3] = fmaf(wv.y, xv.w, acc[1][3]);
      acc[2][0] = fmaf(wv.z, xv.x, acc[2][0]); acc[2][1] = fmaf(wv.z, xv.y, acc[2][1]);
      acc[2][2] = fmaf(wv.z, xv.z, acc[2][2]); acc[2][3] = fmaf(wv.z, xv.w, acc[2][3]);
      acc[3][0] = fmaf(wv.w, xv.x, acc[3][0]); acc[3][1] = fmaf(wv.w, xv.y, acc[3][1]);
      acc[3][2] = fmaf(wv.w, xv.z, acc[3][2]); acc[3][3] = fmaf(wv.w, xv.w, acc[3][3]);
    }
  }
  float* pbase = part + (size_t)blockIdx.y * 64 * 4096;
#pragma unroll
  for (int bb = 0; bb < 4; bb++) {
    int b = bq * 4 + bb;
    float4 o = make_float4(acc[0][bb], acc[1][bb], acc[2][bb], acc[3][bb]);
    *(float4*)&pbase[(size_t)b * 4096 + jbase + jq * 4] = o;
  }
}

// ---------------- attn LSTM pointwise slice + partial q ---------------------------
// grid (64,4): b, hq. 256 thr. h-slice [hq*256, +256). q_part[hq][b][a].
__global__ __launch_bounds__(256) void k_attn_pw(
    const float* __restrict__ part,
    const float* __restrict__ bih, const float* __restrict__ bhh,
    float* __restrict__ ac, float* __restrict__ ah,
    const uint32_t* __restrict__ kf, int s,
    const float* __restrict__ wq, float* __restrict__ qp) {
  const int b = blockIdx.x, hq = blockIdx.y, tid = threadIdx.x;
  __shared__ float ahs[256];
  __shared__ float wtile[128][65];
  __shared__ float qred[128][2];
  const uint32_t fk0 = kf[4 * s], fk1 = kf[4 * s + 1];
  {
    const int h = hq * 256 + tid;
    float gi = bih[h] + bhh[h];
    float gf = bih[h + 1024] + bhh[h + 1024];
    float gg = bih[h + 2048] + bhh[h + 2048];
    float go = bih[h + 3072] + bhh[h + 3072];
    for (int ks = 0; ks < 8; ks++) {
      const float* p = part + (size_t)(ks * 64 + b) * 4096;
      gi += p[h]; gf += p[h + 1024]; gg += p[h + 2048]; go += p[h + 3072];
    }
    float c = sigmf(gf) * ac[b * 1024 + h] + sigmf(gi) * tanhf(gg);
    float hn = sigmf(go) * tanhf(c);
    ac[b * 1024 + h] = c;
    float u = rng_u01(fk0, fk1, (uint32_t)(b * 1024 + h));
    hn = (u < 0.9f) ? hn / 0.9f : 0.0f;
    ah[b * 1024 + h] = hn;
    ahs[tid] = hn;
  }
  const int a = tid & 127, kh = tid >> 7;   // kh in {0,1}: 32-k halves
  float acc = 0.f;
  for (int sub = 0; sub < 4; sub++) {
    const int kbase = hq * 256 + sub * 64;
    __syncthreads();    // wtile reads of prev sub done / ahs ready (first iter)
#pragma unroll
    for (int j = 0; j < 8; j++) {
      int idx = tid + j * 256;             // 2048 float4 slots
      int row = idx >> 4, kc = (idx & 15) << 2;
      *(float4*)&wtile[row][kc] = *(const float4*)&wq[(size_t)row * 1024 + kbase + kc];
    }
    __syncthreads();
    const float* wr = &wtile[a][kh * 32];
    const float* hr = &ahs[sub * 64 + kh * 32];
#pragma unroll
    for (int kk = 0; kk < 32; kk++) acc = fmaf(hr[kk], wr[kk], acc);
  }
  qred[a][kh] = acc;
  __syncthreads();
  if (tid < 128)
    qp[(size_t)(hq * 64 + b) * 128 + tid] = qred[tid][0] + qred[tid][1];
}

// ---------------- energies: loc-conv + loc-dense + tanh + dot v + mask ------------
// grid (B, T/64), 256 thr: t = tid&63, aq = tid>>6 splits f and a ranges
__global__ __launch_bounds__(256) void k_energy(
    const float* __restrict__ aw, const float* __restrict__ awc,
    const float* __restrict__ qp, const float* __restrict__ pm,
    const float* __restrict__ wconv, const float* __restrict__ wld,
    const float* __restrict__ v, const int* __restrict__ mlen,
    float* __restrict__ energ) {
  const int b = blockIdx.x;
  const int t0 = blockIdx.y * 64;
  const int tid = threadIdx.x;
  const int t = tid & 63, aq = tid >> 6;
  __shared__ float sa[2][96];
  __shared__ float sq[128], sv[128];
  __shared__ float sw[1984];
  __shared__ float sld[128][32];
  __shared__ float sloc[64][33];
  __shared__ float spart[64][4];
  for (int i = tid; i < 94; i += 256) {
    int tt = t0 - 15 + i;
    bool ok = (tt >= 0 && tt < 512);
    sa[0][i] = ok ? aw[b * 512 + tt] : 0.0f;
    sa[1][i] = ok ? awc[b * 512 + tt] : 0.0f;
  }
  if (tid < 128) {
    sq[tid] = qp[(size_t)b * 128 + tid] + qp[(size_t)(64 + b) * 128 + tid] +
              qp[(size_t)(128 + b) * 128 + tid] + qp[(size_t)(192 + b) * 128 + tid];
    sv[tid] = v[tid];
  }
  for (int i = tid; i < 1984; i += 256) sw[i] = wconv[i];
  for (int i = tid; i < 4096; i += 256) ((float*)sld)[i] = wld[i];
  __syncthreads();
  const int len = mlen[b];
  const int tt = t0 + t;
  const bool act = (tt < len);
  if (act) {
    for (int f = aq * 8; f < aq * 8 + 8; f++) {
      const float* w0 = sw + f * 62;
      const float* w1 = w0 + 31;
      float a = 0;
#pragma unroll
      for (int k = 0; k < 31; k++) a += sa[0][t + k] * w0[k] + sa[1][t + k] * w1[k];
      sloc[t][f] = a;
    }
  }
  __syncthreads();
  if (act) {
    const float* pmr = pm + (size_t)(b * 512 + tt) * 128;
    float acc = 0;
    for (int a = aq * 32; a < aq * 32 + 32; a++) {
      float pl = 0;
#pragma unroll
      for (int f = 0; f < 32; f++) pl += sloc[t][f] * sld[a][f];
      float x = sq[a] + pl + pmr[a];
      float ex = __expf(2.0f * x);
      acc += sv[a] * (1.0f - 2.0f / (ex + 1.0f));
    }
    spart[t][aq] = acc;
  }
  __syncthreads();
  if (tid < 64) {
    int g = t0 + tid;
    float e = (g < len) ? (spart[tid][0] + spart[tid][1]) + (spart[tid][2] + spart[tid][3]) : -1e9f;
    energ[b * 512 + g] = e;
  }
}

// ---------------- softmax (redundant per block) + ctx slice -----------------------
// grid (64,4): b, ec (128-col slice). 256 thr.
__global__ __launch_bounds__(256) void k_softmax_ctx(
    const float* __restrict__ energ, const int* __restrict__ mlen,
    const float* __restrict__ memv,
    float* __restrict__ aw, float* __restrict__ awc, float* __restrict__ ctx,
    float* __restrict__ out_align, int s) {
  const int b = blockIdx.x, ec = blockIdx.y, tid = threadIdx.x;
  __shared__ float se[512];
  __shared__ float red[4];
  __shared__ float cred[8][132];
  const int len = mlen[b];
  const float e0 = energ[b * 512 + tid];
  const float e1 = energ[b * 512 + 256 + tid];
  float m = fmaxf(e0, e1);
#pragma unroll
  for (int off = 32; off; off >>= 1) m = fmaxf(m, __shfl_xor(m, off, 64));
  if ((tid & 63) == 0) red[tid >> 6] = m;
  __syncthreads();
  const float maxv = fmaxf(fmaxf(red[0], red[1]), fmaxf(red[2], red[3]));
  const float x0 = __expf(e0 - maxv);                      // tid < 256 <= len always
  const float x1 = (tid + 256 < len) ? __expf(e1 - maxv) : 0.0f;
  float sm = x0 + x1;
#pragma unroll
  for (int off = 32; off; off >>= 1) sm += __shfl_xor(sm, off, 64);
  __syncthreads();
  if ((tid & 63) == 0) red[tid >> 6] = sm;
  __syncthreads();
  const float tot = (red[0] + red[1]) + (red[2] + red[3]);
  const float a0 = x0 / tot, a1 = x1 / tot;
  se[tid] = a0; se[tid + 256] = a1;
  if (ec == 0) {
    aw[b * 512 + tid] = a0; aw[b * 512 + 256 + tid] = a1;
    awc[b * 512 + tid] += a0; awc[b * 512 + 256 + tid] += a1;
    float* oa = out_align + (size_t)b * 256000 + (size_t)s * 512;
    oa[tid] = a0; oa[tid + 256] = a1;
  }
  __syncthreads();
  {
    const int c4 = tid & 31, tq = tid >> 5;   // 8 t-phases
    const float4* mb = (const float4*)(memv + (size_t)b * 262144 + ec * 128) + c4;
    float4 c = make_float4(0.f, 0.f, 0.f, 0.f);
    for (int t2 = tq; t2 < len; t2 += 8) {
      float w = se[t2];
      float4 mv = mb[(size_t)t2 * 128];
      c.x = fmaf(w, mv.x, c.x); c.y = fmaf(w, mv.y, c.y);
      c.z = fmaf(w, mv.z, c.z); c.w = fmaf(w, mv.w, c.w);
    }
    *(float4*)&cred[tq][c4 * 4] = c;
  }
  __syncthreads();
  if (tid < 32) {
    float4 c = *(float4*)&cred[0][tid * 4];
#pragma unroll
    for (int i = 1; i < 8; i++) {
      float4 d = *(float4*)&cred[i][tid * 4];
      c.x += d.x; c.y += d.y; c.z += d.z; c.w += d.w;
    }
    *(float4*)&ctx[b * 512 + ec * 128 + tid * 4] = c;
  }
}

// ---------------- melgate body (reads dh_prev/ctx_prev from global) ---------------
__device__ __forceinline__ void melgate_body(
    int b, int sIdx, const float* __restrict__ dhp, const float* __restrict__ ctxp,
    const float* __restrict__ projw, const float* __restrict__ projb,
    const float* __restrict__ gatew, const float* __restrict__ gateb,
    float* __restrict__ out_mel, float* __restrict__ out_gate, int tid,
    float* __restrict__ hcs /*1536*/, float (*ored)[2] /*[128][2]*/) {
  for (int i = tid; i < 1536; i += 256)
    hcs[i] = (i < 1024) ? dhp[b * 1024 + i] : ctxp[b * 512 + (i - 1024)];
  __syncthreads();
  const int mm = tid & 127, seg = tid >> 7;   // 2 segments of 768
  if (mm <= 80) {
    const float* wr = ((mm < 80) ? (projw + (size_t)mm * 1536) : gatew) + seg * 768;
    const float* hs = hcs + seg * 768;
    float a0 = 0, a1 = 0, a2 = 0, a3 = 0;
#pragma unroll 4
    for (int k = 0; k < 768; k += 4) {
      float4 w4 = *(const float4*)(wr + k);
      float4 h4 = *(const float4*)(hs + k);
      a0 = fmaf(h4.x, w4.x, a0); a1 = fmaf(h4.y, w4.y, a1);
      a2 = fmaf(h4.z, w4.z, a2); a3 = fmaf(h4.w, w4.w, a3);
    }
    ored[mm][seg] = (a0 + a1) + (a2 + a3);
  }
  __syncthreads();
  if (tid <= 80) {
    float tot = ored[tid][0] + ored[tid][1];
    if (tid < 80) out_mel[(size_t)b * 40000 + (size_t)sIdx * 80 + tid] = tot + projb[tid];
    else          out_gate[b * 500 + sIdx] = tot + gateb[0];
  }
}

// ---------------- dec LSTM pointwise slice; block hq==0 also does melgate(s-1) ----
__global__ __launch_bounds__(256) void k_dec_pw(
    const float* __restrict__ part,
    const float* __restrict__ bih, const float* __restrict__ bhh,
    float* __restrict__ dc, float* __restrict__ dhn,
    const uint32_t* __restrict__ kf, int s,
    const float* __restrict__ dhp, const float* __restrict__ ctxp,
    const float* __restrict__ projw, const float* __restrict__ projb,
    const float* __restrict__ gatew, const float* __restrict__ gateb,
    float* __restrict__ out_mel, float* __restrict__ out_gate) {
  const int b = blockIdx.x, hq = blockIdx.y, tid = threadIdx.x;
  __shared__ float hcs[1536];
  __shared__ float ored[128][2];
  const uint32_t fk0 = kf[4 * s + 2], fk1 = kf[4 * s + 3];
  {
    const int h = hq * 256 + tid;
    float gi = bih[h] + bhh[h];
    float gf = bih[h + 1024] + bhh[h + 1024];
    float gg = bih[h + 2048] + bhh[h + 2048];
    float go = bih[h + 3072] + bhh[h + 3072];
    for (int ks = 0; ks < 8; ks++) {
      const float* p = part + (size_t)(ks * 64 + b) * 4096;
      gi += p[h]; gf += p[h + 1024]; gg += p[h + 2048]; go += p[h + 3072];
    }
    float c = sigmf(gf) * dc[b * 1024 + h] + sigmf(gi) * tanhf(gg);
    float hn = sigmf(go) * tanhf(c);
    dc[b * 1024 + h] = c;
    float u = rng_u01(fk0, fk1, (uint32_t)(b * 1024 + h));
    hn = (u < 0.9f) ? hn / 0.9f : 0.0f;
    dhn[b * 1024 + h] = hn;
  }
  if (hq == 0 && s > 0) {
    melgate_body(b, s - 1, dhp, ctxp, projw, projb, gatew, gateb,
                 out_mel, out_gate, tid, hcs, ored);
  }
}

// ---------------- epilogue: melgate for s=499 -------------------------------------
__global__ __launch_bounds__(256) void k_mel_final(
    const float* __restrict__ dhp, const float* __restrict__ ctxp,
    const float* __restrict__ projw, const float* __restrict__ projb,
    const float* __restrict__ gatew, const float* __restrict__ gateb,
    float* __restrict__ out_mel, float* __restrict__ out_gate) {
  __shared__ float hcs[1536];
  __shared__ float ored[128][2];
  melgate_body(blockIdx.x, 499, dhp, ctxp, projw, projb, gatew, gateb,
               out_mel, out_gate, threadIdx.x, hcs, ored);
}

extern "C" void kernel_launch(void* const* d_in, const int* in_sizes, int n_in,
                              void* d_out, int out_size, void* d_ws, size_t ws_size,
                              hipStream_t stream) {
  const float* memory = (const float*)d_in[0];
  const int*   mlen   = (const int*)d_in[1];
  const float* dec_in = (const float*)d_in[2];
  const float* pw1    = (const float*)d_in[3];
  const float* pw2    = (const float*)d_in[4];
  const float* awih   = (const float*)d_in[5];
  const float* awhh   = (const float*)d_in[6];
  const float* abih   = (const float*)d_in[7];
  const float* abhh   = (const float*)d_in[8];
  const float* dwih   = (const float*)d_in[9];
  const float* dwhh   = (const float*)d_in[10];
  const float* dbih   = (const float*)d_in[11];
  const float* dbhh   = (const float*)d_in[12];
  const float* wq     = (const float*)d_in[13];
  const float* wm     = (const float*)d_in[14];
  const float* av     = (const float*)d_in[15];
  const float* wconv  = (const float*)d_in[16];
  const float* wld    = (const float*)d_in[17];
  const float* projw  = (const float*)d_in[18];
  const float* projb  = (const float*)d_in[19];
  const float* gatew  = (const float*)d_in[20];
  const float* gateb  = (const float*)d_in[21];

  float* out       = (float*)d_out;
  float* out_mel   = out;                 // B*S*M = 2,560,000
  float* out_gate  = out + 2560000;       // B*S   = 32,000
  float* out_align = out + 2592000;       // B*S*T = 16,384,000

  float* ws      = (float*)d_ws;
  float* pm      = ws;                     // 4,194,304
  float* prenet  = pm + 4194304;           // 8,192,000
  float* part_a  = prenet + 8192000;       // 2,097,152
  float* part_d  = part_a + 2097152;       // 2,097,152
  float* st      = part_d + 2097152;       // states (memset 0):
  float* ah   = st;                        // 65536
  float* ac   = ah + 65536;
  float* dh0  = ac + 65536;
  float* dh1  = dh0 + 65536;
  float* dc   = dh1 + 65536;
  float* aw   = dc + 65536;                // 32768
  float* awc  = aw + 32768;
  float* ctx0 = awc + 32768;               // 32768
  float* ctx1 = ctx0 + 32768;              // 32768
  float* qp   = ctx1 + 32768;              // 4*64*128 = 32768
  float* energ = qp + 32768;               // 32768
  uint32_t* kf = (uint32_t*)(energ + 32768);  // 2000 u32

  hipMemsetAsync(st, 0, (size_t)(5 * 65536 + 4 * 32768) * sizeof(float), stream);
  k_fold<<<4, 256, 0, stream>>>(kf);
  k_pm<<<4096, 256, 0, stream>>>(memory, wm, pm);
  k_prenet1<<<4000, 256, 0, stream>>>(dec_in, pw1, prenet);
  k_prenet2<<<4000, 256, 0, stream>>>(prenet, pw2);

  float* dhb[2]  = { dh0, dh1 };
  float* ctxb[2] = { ctx0, ctx1 };
  for (int s = 0; s < 500; s++) {
    float* ctx_prev = ctxb[(s + 1) & 1];  // ctx(s-1); zeros at s=0 (ctx1 memset)
    float* ctx_cur  = ctxb[s & 1];
    float* dh_prev  = dhb[s & 1];         // dh(s-1); zeros at s=0 (dh0 memset)
    float* dh_next  = dhb[(s + 1) & 1];
    // attention LSTM: x = [prenet_xt(256) | ctx(s-1)(512) | ah(s-1)] ; K = 1792
    k_gemm_part<<<dim3(64, 8), 256, 0, stream>>>(prenet + (size_t)s * 16384, 256,
                                                 ctx_prev, 512, ah, awih, awhh, 768, 224, part_a);
    k_attn_pw<<<dim3(64, 4), 256, 0, stream>>>(part_a, abih, abhh, ac, ah, kf, s, wq, qp);
    k_energy<<<dim3(64, 8), 256, 0, stream>>>(aw, awc, qp, pm, wconv, wld, av, mlen, energ);
    k_softmax_ctx<<<dim3(64, 4), 256, 0, stream>>>(energ, mlen, memory, aw, awc, ctx_cur,
                                                   out_align, s);
    // decoder LSTM: x = [ah(s)(1024) | ctx(s)(512) | dh(s-1)] ; K = 2560
    k_gemm_part<<<dim3(64, 8), 256, 0, stream>>>(ah, 1024, ctx_cur, 512, dh_prev,
                                                 dwih, dwhh, 1536, 320, part_d);
    // dec pointwise writes dh(s)=dh_next; block hq==0 also emits mel/gate(s-1)
    k_dec_pw<<<dim3(64, 4), 256, 0, stream>>>(part_d, dbih, dbhh, dc, dh_next, kf, s,
                                              dh_prev, ctx_prev, projw, projb, gatew, gateb,
                                              out_mel, out_gate);
  }
  // s=499: dh(499) is in dhb[(499+1)&1] = dh0 ; ctx(499) = ctxb[499&1] = ctx1
  k_mel_final<<<64, 256, 0, stream>>>(dh0, ctx1, projw, projb, gatew, gateb,
                                      out_mel, out_gate);
}